// Round 2
// baseline (65.017 us; speedup 1.0000x reference)
//
#include <hip/hip_runtime.h>
#include <hip/hip_bf16.h>

typedef __bf16 bf16_t;
typedef bf16_t bf16x8 __attribute__((ext_vector_type(8)));
typedef float f32x4 __attribute__((ext_vector_type(4)));

#define KD 768
#define BDIM 4096
#define NTILE 32            // 4096/128
#define NBLK (NTILE * (NTILE + 1) / 2)  // 528 upper-triangle tiles

// async global->LDS, 16B per lane; LDS dest must be wave-uniform base (+lane*16 implicit)
#define GLOAD_LDS16(gptr, lptr)                                             \
    __builtin_amdgcn_global_load_lds(                                       \
        (const __attribute__((address_space(1))) unsigned int*)(gptr),      \
        (__attribute__((address_space(3))) unsigned int*)(lptr), 16, 0, 0)

// ---------------- Kernel 1: row-normalize fp32 -> bf16 ----------------
__global__ __launch_bounds__(256) void normalize_rows(
    const float* __restrict__ x, __hip_bfloat16* __restrict__ xn)
{
    const int row = blockIdx.x;
    const int t = threadIdx.x;
    const float* xr = x + (long)row * KD;

    float v[3];
    float ss = 0.f;
#pragma unroll
    for (int i = 0; i < 3; ++i) {
        v[i] = xr[t + 256 * i];
        ss += v[i] * v[i];
    }
#pragma unroll
    for (int off = 32; off > 0; off >>= 1) ss += __shfl_down(ss, off);
    __shared__ float wss[4];
    const int lane = t & 63, wv = t >> 6;
    if (lane == 0) wss[wv] = ss;
    __syncthreads();
    const float tot = wss[0] + wss[1] + wss[2] + wss[3];
    const float inv = 1.0f / fmaxf(sqrtf(tot), 1e-8f);
#pragma unroll
    for (int i = 0; i < 3; ++i)
        xn[(long)row * KD + t + 256 * i] = __float2bfloat16(v[i] * inv);
}

// ---------------- Kernel 2: sim = Xn @ Xn^T (upper triangle), fused Linear(1,2) ----------------
// m97 structure: 128x128 tile, BK=32, 4 waves (2x2), each wave 64x64 = 4x4 frags of 16x16.
// Off-diagonal tiles also write the mirrored tile via an LDS transpose (32-col chunks).
__global__ __launch_bounds__(256) void sim_gemm_sym(
    const bf16_t* __restrict__ Xn,
    const float* __restrict__ fcw, const float* __restrict__ fcb,
    float* __restrict__ out)
{
    __shared__ __align__(16) bf16_t As[128 * 32];   // 8 KB
    __shared__ __align__(16) bf16_t Bs[128 * 32];   // 8 KB
    __shared__ __align__(16) float2 Ts[32][129];    // 32.25 KB transpose staging

    const int tid  = threadIdx.x;
    const int wave = tid >> 6;
    const int lane = tid & 63;

    // decode linear tile id -> (bi, bj) with bi <= bj
    int bi = 0, rem = blockIdx.x;
    while (rem >= NTILE - bi) { rem -= NTILE - bi; ++bi; }
    const int bj = bi + rem;

    const int wr = wave >> 1, wc = wave & 1;

    f32x4 acc[4][4] = {};

    // staging: 512 chunks of 16B per tile; chunk c -> row c>>2, k-offset (c&3)*8
    const int c0  = wave * 64 + lane;
    const int r0  = c0 >> 2, ko0 = (c0 & 3) << 3;
    const int c1  = c0 + 256;
    const int r1  = c1 >> 2, ko1 = (c1 & 3) << 3;

    const bf16_t* gA0 = Xn + (long)(bi * 128 + r0) * KD + ko0;
    const bf16_t* gA1 = Xn + (long)(bi * 128 + r1) * KD + ko1;
    const bf16_t* gB0 = Xn + (long)(bj * 128 + r0) * KD + ko0;
    const bf16_t* gB1 = Xn + (long)(bj * 128 + r1) * KD + ko1;

    bf16_t* lA0 = &As[(wave * 64) * 8];
    bf16_t* lA1 = &As[(wave * 64 + 256) * 8];
    bf16_t* lB0 = &Bs[(wave * 64) * 8];
    bf16_t* lB1 = &Bs[(wave * 64 + 256) * 8];

    const int frow = lane & 15;         // fragment row (A) / col (B)
    const int kg   = (lane >> 4) << 3;  // k-group offset: 0,8,16,24

    for (int k0 = 0; k0 < KD; k0 += 32) {
        GLOAD_LDS16(gA0 + k0, lA0);
        GLOAD_LDS16(gA1 + k0, lA1);
        GLOAD_LDS16(gB0 + k0, lB0);
        GLOAD_LDS16(gB1 + k0, lB1);
        __syncthreads();

        bf16x8 a[4], b[4];
#pragma unroll
        for (int m = 0; m < 4; ++m)
            a[m] = *(const bf16x8*)&As[(wr * 64 + m * 16 + frow) * 32 + kg];
#pragma unroll
        for (int n = 0; n < 4; ++n)
            b[n] = *(const bf16x8*)&Bs[(wc * 64 + n * 16 + frow) * 32 + kg];
#pragma unroll
        for (int m = 0; m < 4; ++m)
#pragma unroll
            for (int n = 0; n < 4; ++n)
                acc[m][n] = __builtin_amdgcn_mfma_f32_16x16x32_bf16(
                    a[m], b[n], acc[m][n], 0, 0, 0);
        __syncthreads();
    }

    const float w0 = fcw[0], w1 = fcw[1];
    const float b0 = fcb[0], b1 = fcb[1];

    // ---- direct write: out[bi-tile rows][bj-tile cols] ----
    const int row0 = bi * 128 + wr * 64 + ((lane >> 4) << 2);
    const int col0 = bj * 128 + wc * 64 + (lane & 15);
#pragma unroll
    for (int m = 0; m < 4; ++m)
#pragma unroll
        for (int n = 0; n < 4; ++n) {
            const int col = col0 + n * 16;
#pragma unroll
            for (int r = 0; r < 4; ++r) {
                const long row = row0 + m * 16 + r;
                const float s = acc[m][n][r];
                float2 v = make_float2(fmaf(s, w0, b0), fmaf(s, w1, b1));
                *(float2*)&out[(row * BDIM + col) * 2] = v;
            }
        }

    if (bi == bj) return;

    // ---- mirror write: out[bj-tile rows][bi-tile cols] via LDS transpose ----
    // 4 chunks of 32 tile-columns each. Chunk c holds tile-cols [c*32, c*32+32).
    // Wave (wc) owns chunk iff wc == c>>1, contributing n = (c&1)*2 + {0,1}.
    const int rl_base = wr * 64 + ((lane >> 4) << 2);
#pragma unroll
    for (int c = 0; c < 4; ++c) {
        if (wc == (c >> 1)) {
#pragma unroll
            for (int np = 0; np < 2; ++np) {
                const int n = ((c & 1) << 1) + np;
                const int ccl = (n & 1) * 16 + (lane & 15);  // 0..31 within chunk
#pragma unroll
                for (int m = 0; m < 4; ++m)
#pragma unroll
                    for (int r = 0; r < 4; ++r) {
                        const float s = acc[m][n][r];
                        Ts[ccl][rl_base + m * 16 + r] =
                            make_float2(fmaf(s, w0, b0), fmaf(s, w1, b1));
                    }
            }
        }
        __syncthreads();
        // write 32 transposed rows: out row = bj*128 + c*32 + i, cols bi*128..+128
        const int l = tid & 63;
        const int i4 = tid >> 6;  // 4 rows per pass
#pragma unroll
        for (int rr = 0; rr < 8; ++rr) {
            const int rowT = rr * 4 + i4;  // 0..31 local
            const float2 v0 = Ts[rowT][l * 2];
            const float2 v1 = Ts[rowT][l * 2 + 1];
            const long og = ((long)(bj * 128 + c * 32 + rowT) * BDIM
                             + bi * 128 + l * 2) * 2;
            *(float4*)&out[og] = make_float4(v0.x, v0.y, v1.x, v1.y);
        }
        __syncthreads();
    }
}

extern "C" void kernel_launch(void* const* d_in, const int* in_sizes, int n_in,
                              void* d_out, int out_size, void* d_ws, size_t ws_size,
                              hipStream_t stream) {
    const float* x   = (const float*)d_in[0];
    const float* fcw = (const float*)d_in[1];
    const float* fcb = (const float*)d_in[2];
    float* out = (float*)d_out;

    __hip_bfloat16* xn = (__hip_bfloat16*)d_ws;  // 4096*768*2B = 6.3 MB

    normalize_rows<<<BDIM, 256, 0, stream>>>(x, xn);

    sim_gemm_sym<<<NBLK, 256, 0, stream>>>((const bf16_t*)xn, fcw, fcb, out);
}

// Round 3
// 55.782 us; speedup vs baseline: 1.1656x; 1.1656x over previous
//
#include <hip/hip_runtime.h>
#include <hip/hip_bf16.h>

typedef __bf16 bf16_t;
typedef bf16_t bf16x8 __attribute__((ext_vector_type(8)));
typedef float f32x4 __attribute__((ext_vector_type(4)));

#define KD 768
#define BDIM 4096
#define NT 12        // K-tiles of BK=64
#define BM 256

#define GLOAD_LDS16(gptr, lptr)                                             \
    __builtin_amdgcn_global_load_lds(                                       \
        (const __attribute__((address_space(1))) unsigned int*)(gptr),      \
        (__attribute__((address_space(3))) unsigned int*)(lptr), 16, 0, 0)

#define BAR()   __builtin_amdgcn_s_barrier()
#define LGKM0() asm volatile("s_waitcnt lgkmcnt(0)" ::: "memory")

// ---------------- Kernel 1: row-normalize fp32 -> bf16 ----------------
__global__ __launch_bounds__(256) void normalize_rows(
    const float* __restrict__ x, __hip_bfloat16* __restrict__ xn)
{
    const int row = blockIdx.x;
    const int t = threadIdx.x;
    const float* xr = x + (long)row * KD;

    float v[3];
    float ss = 0.f;
#pragma unroll
    for (int i = 0; i < 3; ++i) {
        v[i] = xr[t + 256 * i];
        ss += v[i] * v[i];
    }
#pragma unroll
    for (int off = 32; off > 0; off >>= 1) ss += __shfl_down(ss, off);
    __shared__ float wss[4];
    const int lane = t & 63, wv = t >> 6;
    if (lane == 0) wss[wv] = ss;
    __syncthreads();
    const float tot = wss[0] + wss[1] + wss[2] + wss[3];
    const float inv = 1.0f / fmaxf(sqrtf(tot), 1e-8f);
#pragma unroll
    for (int i = 0; i < 3; ++i)
        xn[(long)row * KD + t + 256 * i] = __float2bfloat16(v[i] * inv);
}

// ---------------- Kernel 2: 256x256-tile 8-phase GEMM, fused Linear(1,2) ----------------
// 8 waves (2M x 4N), per-wave output 128x64 (8 M-frags x 4 N-frags of 16x16).
// LDS: 2 K-tile double buffer, A[256][64] + B[256][64] bf16, G4 XOR-swizzle.
// Half-tiles: h0 = A rows 0-127, h1 = A rows 128-255, h2 = B rows 0-127, h3 = B rows 128-255.
// Issue slots (tile t): ph1 -> (t+1).h1, ph2 -> (t+1).h3 (other buffer, always safe);
//                       ph3 -> (t+2).h2 (same buf as t; B-reads done at ph2 barrier-B);
//                       ph4 -> (t+2).h0 (A-reads done at ph3 barrier-B).
// Boundary after tile t: vmcnt(4) (the two (t+2)-halves in flight), vmcnt(0) entering last tile.
__global__ __launch_bounds__(512, 2) void sim_gemm8(
    const bf16_t* __restrict__ Xn,
    const float* __restrict__ fcw, const float* __restrict__ fcb,
    float* __restrict__ out)
{
    __shared__ __align__(16) bf16_t Ab[2][BM * 64];  // 2 x 32 KB
    __shared__ __align__(16) bf16_t Bb[2][BM * 64];  // 2 x 32 KB

    const int tid = threadIdx.x;
    const int wv  = tid >> 6;   // 0..7
    const int ln  = tid & 63;
    const int wm  = wv >> 2;    // 0..1 (M group)
    const int wn  = wv & 3;     // 0..3 (N group)

    const int bi = blockIdx.y, bj = blockIdx.x;
    const int Arow0 = bi * BM, Brow0 = bj * BM;

    // --- staging address precompute (per thread) ---
    // Linear dest byte within 32KB tile: d = hr*16384 + i*8192 + wv*1024 + ln*16.
    // Source element = SWZ(d) where SWZ(b) = b ^ (((b>>7)&7)<<4) (involution).
    int srow[2][2], scole[2][2];
#pragma unroll
    for (int hr = 0; hr < 2; ++hr)
#pragma unroll
        for (int i = 0; i < 2; ++i) {
            const int d = hr * 16384 + i * 8192 + wv * 1024 + ln * 16;
            const int s = d ^ (((d >> 7) & 7) << 4);
            srow[hr][i]  = s >> 7;        // 0..255 within tile
            scole[hr][i] = (s & 127) >> 1; // element offset within 64-elem row
        }

#define ISSUE_HALF(h, tt) do {                                               \
        const int hr_ = (h) & 1;                                             \
        const int bb_ = (tt) & 1;                                            \
        const long rb_ = ((h) < 2 ? Arow0 : Brow0);                          \
        bf16_t* lb_ = ((h) < 2 ? &Ab[bb_][0] : &Bb[bb_][0]);                 \
        _Pragma("unroll")                                                    \
        for (int i_ = 0; i_ < 2; ++i_) {                                     \
            const bf16_t* g_ = Xn + (rb_ + srow[hr_][i_]) * (long)KD         \
                               + (tt) * 64 + scole[hr_][i_];                 \
            bf16_t* l_ = lb_ + (hr_ * 16384 + i_ * 8192 + wv * 1024) / 2;    \
            GLOAD_LDS16(g_, l_);                                             \
        }                                                                    \
    } while (0)

    // --- ds_read addressing: element (row, k) at swizzled byte
    //     row*128 + ((ks*64 + (ln>>4)*16) ^ ((ln&7)<<4)) ---
    const int hi16 = (ln >> 4) << 4;
    const int swzm = (ln & 7) << 4;
    const int ke0 = ((0  + hi16) ^ swzm) >> 1;  // elem offset, ks=0
    const int ke1 = ((64 + hi16) ^ swzm) >> 1;  // elem offset, ks=1
    const int fr  = ln & 15;

    f32x4 acc[8][4] = {};
    bf16x8 a[4][2], b0[2][2], b1[2][2];

#define LDA(MH) do {                                                         \
        _Pragma("unroll")                                                    \
        for (int mf = 0; mf < 4; ++mf) {                                     \
            const int r_ = (wm * 128 + (MH) * 64 + mf * 16 + fr) * 64;       \
            a[mf][0] = *(const bf16x8*)&Ab[bb][r_ + ke0];                    \
            a[mf][1] = *(const bf16x8*)&Ab[bb][r_ + ke1];                    \
        }                                                                    \
    } while (0)

#define LDB(dst, NH) do {                                                    \
        _Pragma("unroll")                                                    \
        for (int nf = 0; nf < 2; ++nf) {                                     \
            const int r_ = (wn * 64 + (NH) * 32 + nf * 16 + fr) * 64;        \
            dst[nf][0] = *(const bf16x8*)&Bb[bb][r_ + ke0];                  \
            dst[nf][1] = *(const bf16x8*)&Bb[bb][r_ + ke1];                  \
        }                                                                    \
    } while (0)

#define MMA(MH, NH, B_) do {                                                 \
        __builtin_amdgcn_s_setprio(1);                                       \
        _Pragma("unroll")                                                    \
        for (int mf = 0; mf < 4; ++mf)                                       \
        _Pragma("unroll")                                                    \
        for (int nf = 0; nf < 2; ++nf)                                       \
        _Pragma("unroll")                                                    \
        for (int ks = 0; ks < 2; ++ks)                                       \
            acc[(MH)*4+mf][(NH)*2+nf] = __builtin_amdgcn_mfma_f32_16x16x32_bf16( \
                a[mf][ks], B_[nf][ks], acc[(MH)*4+mf][(NH)*2+nf], 0, 0, 0);  \
        __builtin_amdgcn_s_setprio(0);                                       \
    } while (0)

    // --- prologue: tile0 all 4 halves + tile1 {h2, h0} ---
    ISSUE_HALF(0, 0); ISSUE_HALF(1, 0); ISSUE_HALF(2, 0); ISSUE_HALF(3, 0);
    ISSUE_HALF(2, 1); ISSUE_HALF(0, 1);
    asm volatile("s_waitcnt vmcnt(4)" ::: "memory");  // tile0 landed; tile1 halves in flight
    BAR();

    for (int t = 0; t < NT; ++t) {
        const int bb = t & 1;

        // phase 1: quadrant (M0, N0)
        LDA(0); LDB(b0, 0);
        if (t + 1 < NT) ISSUE_HALF(1, t + 1);
        BAR(); LGKM0();
        MMA(0, 0, b0);
        BAR();

        // phase 2: quadrant (M0, N1)
        LDB(b1, 1);
        if (t + 1 < NT) ISSUE_HALF(3, t + 1);
        BAR(); LGKM0();
        MMA(0, 1, b1);
        BAR();

        // phase 3: quadrant (M1, N1)
        LDA(1);
        if (t + 2 < NT) ISSUE_HALF(2, t + 2);
        BAR(); LGKM0();
        MMA(1, 1, b1);
        BAR();

        // phase 4: quadrant (M1, N0) — no new ds_reads (b0 kept in regs)
        if (t + 2 < NT) ISSUE_HALF(0, t + 2);
        BAR(); LGKM0();
        MMA(1, 0, b0);
        if (t + 2 < NT)      asm volatile("s_waitcnt vmcnt(4)" ::: "memory");
        else if (t + 1 < NT) asm volatile("s_waitcnt vmcnt(0)" ::: "memory");
        BAR();
    }

    // --- epilogue: fused Linear(1,2), coalesced float2 stores ---
    const float w0 = fcw[0], w1 = fcw[1];
    const float c0 = fcb[0], c1 = fcb[1];
    const int row0 = Arow0 + wm * 128 + ((ln >> 4) << 2);
    const int col0 = Brow0 + wn * 64 + fr;
#pragma unroll
    for (int mi = 0; mi < 8; ++mi)
#pragma unroll
        for (int ni = 0; ni < 4; ++ni) {
            const int col = col0 + ni * 16;
#pragma unroll
            for (int r = 0; r < 4; ++r) {
                const long row = row0 + mi * 16 + r;
                const float s = acc[mi][ni][r];
                *(float2*)&out[(row * BDIM + col) * 2] =
                    make_float2(fmaf(s, w0, c0), fmaf(s, w1, c1));
            }
        }

#undef ISSUE_HALF
#undef LDA
#undef LDB
#undef MMA
}

extern "C" void kernel_launch(void* const* d_in, const int* in_sizes, int n_in,
                              void* d_out, int out_size, void* d_ws, size_t ws_size,
                              hipStream_t stream) {
    const float* x   = (const float*)d_in[0];
    const float* fcw = (const float*)d_in[1];
    const float* fcb = (const float*)d_in[2];
    float* out = (float*)d_out;

    __hip_bfloat16* xn = (__hip_bfloat16*)d_ws;  // 4096*768*2B = 6.3 MB

    normalize_rows<<<BDIM, 256, 0, stream>>>(x, xn);

    dim3 grid(BDIM / BM, BDIM / BM);  // 16 x 16
    sim_gemm8<<<grid, 512, 0, stream>>>((const bf16_t*)xn, fcw, fcb, out);
}